// Round 5
// baseline (2293.979 us; speedup 1.0000x reference)
//
#include <hip/hip_runtime.h>
#include <math.h>

#define CH 86
#define SP 54
#define SS2 2916
#define SS3 157464
#define DG 48
#define MPAD 157568          /* 1231*128 */
#define RT_ROWS (CH*SS2)     /* 250776 rows of (i,x,y) */
#define NSLICE (CH*SP)       /* 4644 */
#define PI_F 3.14159265358979323846f
#define GN_INV (1.0/13541904.0)

static constexpr size_t A512(size_t x){ return (x + 511) & ~((size_t)511); }
static constexpr size_t HB2 = (size_t)CH*SS3*2;               // 27 MB  (hA bf16 [c][s])
static constexpr size_t HB4 = (size_t)CH*SS3*4;               // 54 MB  (hS fp32 [c][s])
static constexpr size_t AB2 = (size_t)MPAD*96*2;              // 30 MB  (bf16 [s][96])
static constexpr size_t XB4 = (size_t)MPAD*96*4;              // 60.5MB (fp32 [s][96])
static constexpr size_t FAB = (size_t)CH*SS2*6*8;
static constexpr size_t FBB = (size_t)CH*SP*12*6*8;
static constexpr size_t FCB = (size_t)CH*864*8;
static constexpr size_t OFF_HA = 0;                           // hA bf16
static constexpr size_t OFF_HS = OFF_HA + A512(HB2);          // hS fp32
static constexpr size_t OFF_AB = OFF_HS + A512(HB4);
static constexpr size_t OFF_BB = OFF_AB + A512(AB2);
static constexpr size_t OFF_XSC= OFF_BB + A512(AB2);          // Hm fp32 [s][96]; FY at l=3
static constexpr size_t OFF_FA = OFF_XSC+ A512(XB4);
static constexpr size_t OFF_FB = OFF_FA + A512(FAB);
static constexpr size_t OFF_FC = OFF_FB + A512(FBB);
static constexpr size_t OFF_FD = OFF_FC + A512(FCB);
static constexpr size_t OFF_FE = OFF_FD + A512(FCB);
static constexpr size_t OFF_ST = OFF_FE + A512(FBB);
static constexpr size_t OFF_WB = OFF_ST + 512;                // 16 conv weights bf16 [96][96]
static constexpr size_t OFF_P1W= OFF_WB + A512((size_t)16*96*96*2);
static constexpr size_t OFF_W1 = OFF_P1W+ A512((size_t)256*96*2);
static constexpr size_t OFF_W2 = OFF_W1 + A512((size_t)512*96*2);
static constexpr size_t OFF_W3 = OFF_W2 + A512((size_t)256*512*2);
static constexpr size_t OFF_K3 = OFF_W3 + A512((size_t)86*256*2);     // fp32 [196608][86]
static constexpr size_t OFF_Z2 = OFF_K3 + A512((size_t)196608*CH*4);
static constexpr size_t OFF_U  = OFF_Z2 + A512((size_t)98304*256*2);
static constexpr size_t OFF_H1 = OFF_U  + A512((size_t)8192*96*2);
// hT bf16 [MPAD][96] aliases K3 (FNO phase only; K3 written after FNO done)
static constexpr size_t OFF_HT = OFF_K3;
// GNO big scratch overlays [0..OFF_XSC): kin + Z1
static constexpr int    CHUNK_M = 98304;
static constexpr size_t OFF_KIN = 0;
static constexpr size_t OFF_Z1  = A512((size_t)CHUNK_M*96*2);

typedef __attribute__((ext_vector_type(8))) short bf16x8;
typedef __attribute__((ext_vector_type(4))) float f32x4;

__device__ __forceinline__ float gelu_f(float x){
  return 0.5f*x*(1.0f + erff(x*0.70710678118654752440f));
}
__device__ __forceinline__ unsigned short f2bf(float x){
  unsigned u = __float_as_uint(x);
  u += 0x7fffu + ((u>>16)&1u);
  return (unsigned short)(u>>16);
}
__device__ __forceinline__ float bf2f(unsigned short u){
  return __uint_as_float(((unsigned)u)<<16);
}

__global__ void k_zero_stats(double* st){ if (threadIdx.x < 16) st[threadIdx.x] = 0.0; }

__global__ __launch_bounds__(256) void k_f2bf(const float* __restrict__ in,
    unsigned short* __restrict__ out, int n)
{
  int i = blockIdx.x*256 + threadIdx.x;
  if (i < n) out[i] = f2bf(in[i]);
}

// conv weight prep: [86][86] fp32 -> [96][96] bf16 zero-padded
__global__ __launch_bounds__(256) void k_wprep(const float* __restrict__ src,
    unsigned short* __restrict__ dst, int slot)
{
  int l = blockIdx.y;
  int idx = blockIdx.x*256 + threadIdx.x;
  int n = idx/96, k = idx-96*n;
  unsigned short v = 0;
  if (n < 86 && k < 86) v = f2bf(src[(size_t)l*7396 + n*86 + k]);
  dst[(size_t)(l*4+slot)*9216 + idx] = v;
}

// pad [rows][86] fp32 -> [rows][96] bf16
__global__ __launch_bounds__(256) void k_pad_w(const float* __restrict__ src,
    unsigned short* __restrict__ dst, int rows)
{
  int idx = blockIdx.x*256 + threadIdx.x;
  if (idx >= rows*96) return;
  int n = idx/96, k = idx-96*n;
  dst[idx] = (k<86)? f2bf(src[n*86+k]) : (unsigned short)0;
}

// ---------------- lift: writes hA bf16 [c][s] + Ab bf16 [s][96] ----------------
__global__ __launch_bounds__(256) void k_lift(const float* __restrict__ df,
    const float* __restrict__ wl, const float* __restrict__ bl,
    unsigned short* __restrict__ hA, unsigned short* __restrict__ Ab)
{
  __shared__ float vals[128*96];
  const int t = threadIdx.x;
  const int s0 = blockIdx.x*128;
  for(int idx=t; idx<128*96; idx+=256){
    int sl = idx/96, o = idx-96*sl;
    int s = s0+sl;
    float v = 0.f;
    if (o < 86){
      int x = s/2916, r2 = s-2916*x, y = r2/54, z = r2-54*y;
      if (x<DG && y<DG && z<DG){
        int p = (x*DG + y)*DG + z;
        v = wl[o*5]*df[p] + wl[o*5+1]*df[110592+p]
          + wl[o*5+2]*(x*(1.0f/47.0f)) + wl[o*5+3]*(y*(1.0f/47.0f))
          + wl[o*5+4]*(z*(1.0f/47.0f)) + bl[o];
      }
    }
    vals[idx] = v;
  }
  __syncthreads();
  for(int idx=t; idx<128*96; idx+=256)
    Ab[(size_t)s0*96 + idx] = f2bf(vals[idx]);
  for(int idx=t; idx<86*128; idx+=256){
    int c = idx/128, sl = idx-128*c;
    int s = s0+sl;
    if (s < SS3) hA[(size_t)c*SS3 + s] = f2bf(vals[sl*96 + c]);
  }
}

// ---------------- forward partial DFT ----------------
__global__ __launch_bounds__(256) void k_dft_z(const unsigned short* __restrict__ h, float* __restrict__ A)
{
  __shared__ alignas(16) float rows[64*55];
  __shared__ float twc[6*54], tws[6*54];
  const int t = threadIdx.x;
  for(int idx=t; idx<6*54; idx+=256){
    int k = idx/54, z = idx-54*k;
    int m = (k*z)%54;
    float ang = -(2.0f*PI_F/54.0f)*(float)m;
    twc[idx]=cosf(ang); tws[idx]=sinf(ang);
  }
  const int r0 = blockIdx.x*64;
  for(int idx=t; idx<64*54; idx+=256){
    int r = idx/54;
    rows[r*55 + (idx-54*r)] = (r0+r < RT_ROWS)? bf2f(h[(size_t)r0*54 + idx]) : 0.f;
  }
  __syncthreads();
  for(int oi=t; oi<768; oi+=256){
    int r = oi & 63;
    int k = (oi>>6)%6;
    int part = oi/384;
    if (r0+r < RT_ROWS){
      const float* tw = part? tws : twc;
      const float* rp = &rows[r*55];
      const float* twk = &tw[k*54];
      float acc=0.f;
      #pragma unroll 6
      for(int z=0;z<54;z++) acc += rp[z]*twk[z];
      A[((size_t)(r0+r)*6 + k)*2 + part] = acc;
    }
  }
}

__global__ __launch_bounds__(256) void k_dft_y(const float* __restrict__ A, float* __restrict__ B)
{
  __shared__ float asl[4*648];
  __shared__ float twc[12*54], tws[12*54];
  const int t = threadIdx.x;
  for(int idx=t; idx<12*54; idx+=256){
    int kyi = idx/54, y = idx-54*kyi;
    int ky = (kyi<6)? kyi : (42+kyi);
    int m = (ky*y)%54;
    float ang = -(2.0f*PI_F/54.0f)*(float)m;
    twc[idx]=cosf(ang); tws[idx]=sinf(ang);
  }
  const int s0 = blockIdx.x*4;
  for(int idx=t; idx<4*648; idx+=256){
    int sl = idx/648;
    asl[idx] = (s0+sl < NSLICE)? A[(size_t)s0*648 + idx] : 0.f;
  }
  __syncthreads();
  for(int oi=t; oi<4*72; oi+=256){
    int sl = oi/72, o = oi-72*sl;
    if (s0+sl >= NSLICE) continue;
    int kyi = o/6, kz = o-6*kyi;
    const float* base = &asl[sl*648];
    float cr=0.f, ci=0.f;
    for(int y=0;y<54;y++){
      float ar = base[(y*6+kz)*2], ai = base[(y*6+kz)*2+1];
      float tc = twc[kyi*54+y], ts = tws[kyi*54+y];
      cr += ar*tc - ai*ts;
      ci += ar*ts + ai*tc;
    }
    size_t ob = ((size_t)(s0+sl)*12 + kyi)*6 + kz;
    B[ob*2]=cr; B[ob*2+1]=ci;
  }
}

__global__ __launch_bounds__(256) void k_dft_x(const float* __restrict__ B, float* __restrict__ C)
{
  __shared__ float bsl[7776];
  __shared__ float twc[12*54], tws[12*54];
  const int t = threadIdx.x;
  const int i = blockIdx.x;
  for(int idx=t; idx<12*54; idx+=256){
    int kxi = idx/54, x = idx-54*kxi;
    int kx = (kxi<6)? kxi : (42+kxi);
    int m = (kx*x)%54;
    float ang = -(2.0f*PI_F/54.0f)*(float)m;
    twc[idx]=cosf(ang); tws[idx]=sinf(ang);
  }
  for(int idx=t; idx<7776; idx+=256) bsl[idx] = B[(size_t)i*7776 + idx];
  __syncthreads();
  for(int oi=t; oi<864; oi+=256){
    int kxi = oi/72, rest = oi-72*kxi;
    float cr=0.f, ci=0.f;
    for(int x=0;x<54;x++){
      float br = bsl[(x*72+rest)*2], bi = bsl[(x*72+rest)*2+1];
      float tc = twc[kxi*54+x], ts = tws[kxi*54+x];
      cr += br*tc - bi*ts;
      ci += br*ts + bi*tc;
    }
    int kyi = rest/6, kz = rest-6*kyi;
    int c = ((kxi>=6)?2:0) + ((kyi>=6)?1:0);
    int f = ((kxi%6)*6 + (kyi%6))*6 + kz;
    size_t ob = ((size_t)i*4 + c)*216 + f;
    C[ob*2]=cr; C[ob*2+1]=ci;
  }
}

__global__ __launch_bounds__(256) void k_mix(const float* __restrict__ C,
    const float* __restrict__ wr, const float* __restrict__ wi, float* __restrict__ D)
{
  const int f = threadIdx.x;
  if (f >= 216) return;
  const int o = blockIdx.x, c = blockIdx.y;
  const size_t wstride = (size_t)CH*216;
  const float* wrp = wr + ((size_t)c*CH*CH + o)*216 + f;
  const float* wip = wi + ((size_t)c*CH*CH + o)*216 + f;
  const float* cp  = C + ((size_t)c*216 + f)*2;
  float ar=0.f, ai=0.f;
  #pragma unroll 4
  for(int i=0;i<CH;i++){
    float cr = cp[0], cim = cp[1];
    float xr = *wrp, xi = *wip;
    ar += cr*xr - cim*xi;
    ai += cr*xi + cim*xr;
    wrp += wstride; wip += wstride;
    cp += 864*2;
  }
  int mx = f/36, my = (f/6)%6, kz = f%6;
  int kxi = mx + ((c>=2)?6:0);
  int kyi = my + ((c&1)?6:0);
  size_t ob = (((size_t)o*12 + kxi)*12 + kyi)*6 + kz;
  D[ob*2]=ar; D[ob*2+1]=ai;
}

// ---------------- inverse partial DFT ----------------
__global__ __launch_bounds__(256) void k_idft_x(const float* __restrict__ D, float* __restrict__ E)
{
  __shared__ float dsl[1728];
  __shared__ float twc[12*54], tws[12*54];
  const int t = threadIdx.x;
  const int o = blockIdx.x;
  for(int idx=t; idx<12*54; idx+=256){
    int kxi = idx/54, x = idx-54*kxi;
    int kx = (kxi<6)? kxi : (42+kxi);
    int m = (kx*x)%54;
    float ang = (2.0f*PI_F/54.0f)*(float)m;
    twc[idx]=cosf(ang); tws[idx]=sinf(ang);
  }
  for(int idx=t; idx<1728; idx+=256) dsl[idx] = D[(size_t)o*1728 + idx];
  __syncthreads();
  for(int oi=t; oi<3888; oi+=256){
    int x = oi/72, rest = oi-72*x;
    float er=0.f, ei=0.f;
    #pragma unroll
    for(int kxi=0;kxi<12;kxi++){
      float dr = dsl[(kxi*72+rest)*2], di = dsl[(kxi*72+rest)*2+1];
      float tc = twc[kxi*54+x], ts = tws[kxi*54+x];
      er += dr*tc - di*ts;
      ei += dr*ts + di*tc;
    }
    size_t ob = (size_t)o*3888 + oi;
    E[ob*2]=er; E[ob*2+1]=ei;
  }
}

__global__ __launch_bounds__(256) void k_idft_y(const float* __restrict__ E, float* __restrict__ F)
{
  __shared__ float esl[4*144];
  __shared__ float twc[12*54], tws[12*54];
  const int t = threadIdx.x;
  for(int idx=t; idx<12*54; idx+=256){
    int kyi = idx/54, y = idx-54*kyi;
    int ky = (kyi<6)? kyi : (42+kyi);
    int m = (ky*y)%54;
    float ang = (2.0f*PI_F/54.0f)*(float)m;
    twc[idx]=cosf(ang); tws[idx]=sinf(ang);
  }
  const int s0 = blockIdx.x*4;
  for(int idx=t; idx<4*144; idx+=256){
    int sl = idx/144;
    esl[idx] = (s0+sl < NSLICE)? E[(size_t)s0*144 + idx] : 0.f;
  }
  __syncthreads();
  for(int oi=t; oi<4*324; oi+=256){
    int sl = oi/324, rest = oi-324*sl;
    if (s0+sl >= NSLICE) continue;
    int y = rest/6, kz = rest-6*y;
    const float* base = &esl[sl*144];
    float fr=0.f, fi=0.f;
    #pragma unroll
    for(int kyi=0;kyi<12;kyi++){
      float er = base[(kyi*6+kz)*2], ei = base[(kyi*6+kz)*2+1];
      float tc = twc[kyi*54+y], ts = tws[kyi*54+y];
      fr += er*tc - ei*ts;
      fi += er*ts + ei*tc;
    }
    size_t ob = ((size_t)(s0+sl)*54 + y)*6 + kz;
    F[ob*2]=fr; F[ob*2+1]=fi;
  }
}

__global__ __launch_bounds__(256) void k_idft_z(const float* __restrict__ F,
    float* __restrict__ hs, double* __restrict__ st)
{
  __shared__ float rws[64*12];
  __shared__ float twc[5*54], tws[5*54];
  __shared__ float red[8];
  const int t = threadIdx.x;
  for(int idx=t; idx<5*54; idx+=256){
    int k = idx/54 + 1, z = idx%54;
    int m = (k*z)%54;
    float ang = (2.0f*PI_F/54.0f)*(float)m;
    twc[idx]=cosf(ang); tws[idx]=sinf(ang);
  }
  const int r0 = blockIdx.x*64;
  for(int idx=t; idx<768; idx+=256){
    int r = idx/12;
    rws[idx] = (r0+r < RT_ROWS)? F[(size_t)r0*12 + idx] : 0.f;
  }
  __syncthreads();
  const float inv = 1.0f/157464.0f;
  float lsum=0.f, lsq=0.f;
  for(int oi=t; oi<64*54; oi+=256){
    int r = oi/54, z = oi-54*r;
    if (r0+r < RT_ROWS){
      const float* fr = &rws[r*12];
      float acc = fr[0];
      #pragma unroll
      for(int k=1;k<=5;k++)
        acc += 2.0f*(fr[2*k]*twc[(k-1)*54+z] - fr[2*k+1]*tws[(k-1)*54+z]);
      acc *= inv;
      hs[(size_t)r0*54 + oi] = acc;
      lsum += acc; lsq += acc*acc;
    }
  }
  #pragma unroll
  for(int off=32; off; off>>=1){
    lsum += __shfl_down(lsum, off, 64);
    lsq  += __shfl_down(lsq,  off, 64);
  }
  if ((t&63)==0){ red[(t>>6)*2]=lsum; red[(t>>6)*2+1]=lsq; }
  __syncthreads();
  if (t==0){
    double s1 = (double)red[0]+red[2]+red[4]+red[6];
    double s2 = (double)red[1]+red[3]+red[5]+red[7];
    atomicAdd(st, s1); atomicAdd(st+1, s2);
  }
}

// ---------------- transpose hS fp32 [c][s] -> hT bf16 [s][96] ----------------
__global__ __launch_bounds__(256) void k_tr(const float* __restrict__ hS,
    unsigned short* __restrict__ hT)
{
  __shared__ float tile[128*101];   // stride 101: conflict-free both phases
  const int t = threadIdx.x;
  const int s0 = blockIdx.x*128;
  for(int idx=t; idx<86*128; idx+=256){
    int c = idx>>7, sl = idx&127;
    int s = s0+sl;
    tile[sl*101+c] = (s<SS3)? hS[(size_t)c*SS3+s] : 0.f;
  }
  for(int idx=t; idx<128*10; idx+=256){
    int sl = idx/10, c = 86 + idx%10;
    tile[sl*101+c] = 0.f;
  }
  __syncthreads();
  for(int idx=t; idx<1536; idx+=256){
    int r = idx/12, g = idx-12*r;
    bf16x8 o;
    #pragma unroll
    for(int j=0;j<8;j++) o[j] = (short)f2bf(tile[r*101+g*8+j]);
    *(bf16x8*)&hT[(size_t)(s0+r)*96 + g*8] = o;
  }
}

// ---------------- fused skip + m1 + m2 (per 128-row tile) ----------------
// P1: Bb = act1(gn1(hT) + Ab@Wskip + bskip);  P2: T = gelu(T@Wm1 + b1);
// P3: Hm = T@Wm2 + b2 (fp32 [s][96]) + global stats.
// A-fragments direct global->register; W in LDS padded stride 104 (2-way = free).
template<int ACT1>
__global__ __launch_bounds__(256) void k_fuse3(
    const unsigned short* __restrict__ Ain, const unsigned short* __restrict__ Wl3,
    const float* __restrict__ bsk, const float* __restrict__ b1,
    const float* __restrict__ b2,
    const unsigned short* __restrict__ hT, const float* __restrict__ g1,
    const float* __restrict__ bg1, const double* __restrict__ st1,
    double* __restrict__ st2,
    unsigned short* __restrict__ Bb, float* __restrict__ Hm)
{
  __shared__ alignas(16) unsigned short Wl[96*104];
  __shared__ alignas(16) unsigned short T[128*104];
  __shared__ float red[8];
  const int t = threadIdx.x, lane = t&63, w = t>>6;
  const int m0 = blockIdx.x*128;
  const int colb = lane&15, rowq = (lane>>4)*4, half = lane>>4;
  f32x4 acc[2][6];

  // stage Wskip (padded) + hT tile
  for(int idx=t; idx<1152; idx+=256){
    int r = idx/12, g = idx-12*r;
    *(bf16x8*)&Wl[r*104+g*8] = *(const bf16x8*)&Wl3[r*96+g*8];
  }
  for(int idx=t; idx<1536; idx+=256){
    int r = idx/12, g = idx-12*r;
    *(bf16x8*)&T[r*104+g*8] = *(const bf16x8*)&hT[(size_t)(m0+r)*96 + g*8];
  }
  // A fragments direct from global
  bf16x8 afr[2][3];
  {
    const unsigned short* Abase = Ain + (size_t)(m0 + w*32 + colb)*96 + half*8;
    #pragma unroll
    for(int s=0;s<2;s++)
      #pragma unroll
      for(int q=0;q<3;q++)
        afr[s][q] = *(const bf16x8*)(Abase + s*16*96 + q*32);
  }
  #pragma unroll
  for(int s=0;s<2;s++)
    #pragma unroll
    for(int n=0;n<6;n++) acc[s][n] = (f32x4){0.f,0.f,0.f,0.f};
  __syncthreads();                       // B1: Wl + T ready
  #pragma unroll
  for(int q=0;q<3;q++){
    bf16x8 bf[6];
    #pragma unroll
    for(int n=0;n<6;n++)
      bf[n] = *(const bf16x8*)&Wl[(n*16+colb)*104 + q*32 + half*8];
    #pragma unroll
    for(int s=0;s<2;s++)
      #pragma unroll
      for(int n=0;n<6;n++)
        acc[s][n] = __builtin_amdgcn_mfma_f32_16x16x32_bf16(afr[s][q], bf[n], acc[s][n], 0, 0, 0);
  }
  // P1 epilogue: gn1-add from T (thread-owned addresses), write back to T
  {
    double m = st1[0]*GN_INV;
    double va = st1[1]*GN_INV - m*m;
    float mu = (float)m, rs = (float)(1.0/sqrt(va + 1e-5));
    #pragma unroll
    for(int n=0;n<6;n++){
      int col = n*16 + colb;
      bool cv = (col < CH);
      float bn=0.f, gg=1.f, bb=0.f;
      if (cv){ bn = bsk[col]; gg = g1[col]; bb = bg1[col]; }
      #pragma unroll
      for(int s=0;s<2;s++){
        #pragma unroll
        for(int r=0;r<4;r++){
          int rowl = w*32 + s*16 + rowq + r;
          float v = 0.f;
          if (cv){
            v = acc[s][n][r] + bn + (bf2f(T[rowl*104+col])-mu)*rs*gg + bb;
            if (ACT1) v = gelu_f(v);
          }
          T[rowl*104+col] = f2bf(v);
        }
      }
    }
  }
  __syncthreads();                       // B2: T = h1 complete
  // coalesced Bb write + load Wm1
  for(int idx=t; idx<1536; idx+=256){
    int r = idx/12, g = idx-12*r;
    *(bf16x8*)&Bb[(size_t)(m0+r)*96 + g*8] = *(const bf16x8*)&T[r*104+g*8];
  }
  for(int idx=t; idx<1152; idx+=256){
    int r = idx/12, g = idx-12*r;
    *(bf16x8*)&Wl[r*104+g*8] = *(const bf16x8*)&Wl3[9216 + r*96+g*8];
  }
  __syncthreads();                       // B3
  // P2: m1 (A from own-wave T rows)
  #pragma unroll
  for(int s=0;s<2;s++)
    #pragma unroll
    for(int n=0;n<6;n++) acc[s][n] = (f32x4){0.f,0.f,0.f,0.f};
  #pragma unroll
  for(int q=0;q<3;q++){
    bf16x8 a2[2], bf[6];
    #pragma unroll
    for(int s=0;s<2;s++)
      a2[s] = *(const bf16x8*)&T[(w*32+s*16+colb)*104 + q*32 + half*8];
    #pragma unroll
    for(int n=0;n<6;n++)
      bf[n] = *(const bf16x8*)&Wl[(n*16+colb)*104 + q*32 + half*8];
    #pragma unroll
    for(int s=0;s<2;s++)
      #pragma unroll
      for(int n=0;n<6;n++)
        acc[s][n] = __builtin_amdgcn_mfma_f32_16x16x32_bf16(a2[s], bf[n], acc[s][n], 0, 0, 0);
  }
  #pragma unroll
  for(int n=0;n<6;n++){
    int col = n*16 + colb;
    bool cv = (col < CH);
    float bn = cv? b1[col] : 0.f;
    #pragma unroll
    for(int s=0;s<2;s++){
      #pragma unroll
      for(int r=0;r<4;r++){
        int rowl = w*32 + s*16 + rowq + r;
        float v = cv? gelu_f(acc[s][n][r] + bn) : 0.f;
        T[rowl*104+col] = f2bf(v);
      }
    }
  }
  __syncthreads();                       // B4
  for(int idx=t; idx<1152; idx+=256){
    int r = idx/12, g = idx-12*r;
    *(bf16x8*)&Wl[r*104+g*8] = *(const bf16x8*)&Wl3[18432 + r*96+g*8];
  }
  __syncthreads();                       // B5
  // P3: m2
  #pragma unroll
  for(int s=0;s<2;s++)
    #pragma unroll
    for(int n=0;n<6;n++) acc[s][n] = (f32x4){0.f,0.f,0.f,0.f};
  #pragma unroll
  for(int q=0;q<3;q++){
    bf16x8 a2[2], bf[6];
    #pragma unroll
    for(int s=0;s<2;s++)
      a2[s] = *(const bf16x8*)&T[(w*32+s*16+colb)*104 + q*32 + half*8];
    #pragma unroll
    for(int n=0;n<6;n++)
      bf[n] = *(const bf16x8*)&Wl[(n*16+colb)*104 + q*32 + half*8];
    #pragma unroll
    for(int s=0;s<2;s++)
      #pragma unroll
      for(int n=0;n<6;n++)
        acc[s][n] = __builtin_amdgcn_mfma_f32_16x16x32_bf16(a2[s], bf[n], acc[s][n], 0, 0, 0);
  }
  float lsum=0.f, lsq=0.f;
  #pragma unroll
  for(int n=0;n<6;n++){
    int col = n*16 + colb;
    bool cv = (col < CH);
    float bn = cv? b2[col] : 0.f;
    #pragma unroll
    for(int s=0;s<2;s++){
      #pragma unroll
      for(int r=0;r<4;r++){
        int row = m0 + w*32 + s*16 + rowq + r;
        float v = 0.f;
        if (cv){
          v = acc[s][n][r] + bn;
          if (row < SS3){ lsum += v; lsq += v*v; }
        }
        Hm[(size_t)row*96 + col] = v;
      }
    }
  }
  #pragma unroll
  for(int off=32; off; off>>=1){
    lsum += __shfl_down(lsum, off, 64);
    lsq  += __shfl_down(lsq,  off, 64);
  }
  if (lane==0){ red[w*2]=lsum; red[w*2+1]=lsq; }
  __syncthreads();
  if (t==0){
    double s1 = (double)red[0]+red[2]+red[4]+red[6];
    double s2 = (double)red[1]+red[3]+red[5]+red[7];
    atomicAdd(st2, s1); atomicAdd(st2+1, s2);
  }
}

// ---------------- ms conv + gn2 combine: h = act(gn2(Hm) + Bb@Wms + bms) ----------------
// LAST=0: Ab bf16 [s][96] + hA bf16 [c][s] (both via LDS, coalesced); LAST=1: FY fp32 [s][96]
template<int LAST>
__global__ __launch_bounds__(256) void k_convms(
    const unsigned short* __restrict__ Ain, const unsigned short* __restrict__ Wm,
    const float* __restrict__ bms,
    const float* __restrict__ Hm, const float* __restrict__ g2,
    const float* __restrict__ bg2, const double* __restrict__ st2,
    unsigned short* __restrict__ Ab, unsigned short* __restrict__ hA,
    float* __restrict__ FY)
{
  __shared__ alignas(16) unsigned short Wl[96*104];
  __shared__ alignas(16) unsigned short T[128*104];
  const int t = threadIdx.x, lane = t&63, w = t>>6;
  const int m0 = blockIdx.x*128;
  const int colb = lane&15, rowq = (lane>>4)*4, half = lane>>4;
  for(int idx=t; idx<1152; idx+=256){
    int r = idx/12, g = idx-12*r;
    *(bf16x8*)&Wl[r*104+g*8] = *(const bf16x8*)&Wm[r*96+g*8];
  }
  bf16x8 afr[2][3];
  {
    const unsigned short* Abase = Ain + (size_t)(m0 + w*32 + colb)*96 + half*8;
    #pragma unroll
    for(int s=0;s<2;s++)
      #pragma unroll
      for(int q=0;q<3;q++)
        afr[s][q] = *(const bf16x8*)(Abase + s*16*96 + q*32);
  }
  f32x4 acc[2][6];
  #pragma unroll
  for(int s=0;s<2;s++)
    #pragma unroll
    for(int n=0;n<6;n++) acc[s][n] = (f32x4){0.f,0.f,0.f,0.f};
  __syncthreads();
  #pragma unroll
  for(int q=0;q<3;q++){
    bf16x8 bf[6];
    #pragma unroll
    for(int n=0;n<6;n++)
      bf[n] = *(const bf16x8*)&Wl[(n*16+colb)*104 + q*32 + half*8];
    #pragma unroll
    for(int s=0;s<2;s++)
      #pragma unroll
      for(int n=0;n<6;n++)
        acc[s][n] = __builtin_amdgcn_mfma_f32_16x16x32_bf16(afr[s][q], bf[n], acc[s][n], 0, 0, 0);
  }
  double m = st2[0]*GN_INV;
  double va = st2[1]*GN_INV - m*m;
  float mu = (float)m, rs = (float)(1.0/sqrt(va + 1e-5));
  #pragma unroll
  for(int n=0;n<6;n++){
    int col = n*16 + colb;
    bool cv = (col < CH);
    float bn=0.f, gg=1.f, bb=0.f;
    if (cv){ bn = bms[col]; gg = g2[col]; bb = bg2[col]; }
    #pragma unroll
    for(int s=0;s<2;s++){
      #pragma unroll
      for(int r=0;r<4;r++){
        int rowl = w*32 + s*16 + rowq + r;
        int row = m0 + rowl;
        float v = 0.f;
        if (cv){
          v = acc[s][n][r] + bn + (Hm[(size_t)row*96 + col]-mu)*rs*gg + bb;
          if (!LAST) v = gelu_f(v);
        }
        if (LAST) FY[(size_t)row*96 + col] = v;
        else      T[rowl*104+col] = f2bf(v);
      }
    }
  }
  if (!LAST){
    __syncthreads();
    for(int idx=t; idx<1536; idx+=256){
      int r = idx/12, g = idx-12*r;
      *(bf16x8*)&Ab[(size_t)(m0+r)*96 + g*8] = *(const bf16x8*)&T[r*104+g*8];
    }
    for(int idx=t; idx<86*64; idx+=256){
      int c = idx>>6, p = idx&63;
      int s = m0 + 2*p;
      if (s < SS3){
        unsigned v2 = (unsigned)T[(2*p)*104+c] | ((unsigned)T[(2*p+1)*104+c] << 16);
        *(unsigned*)(hA + (size_t)c*SS3 + s) = v2;
      }
    }
  }
}

// ---------------- kin: [pair][96] bf16 = [y-embed(48) | q-embed(48)] ----------------
__global__ __launch_bounds__(256) void k_build_kin(const float* __restrict__ x_in,
    const int* __restrict__ nb_idx, unsigned short* __restrict__ kin, int pair0)
{
  int gidx = blockIdx.x*256 + threadIdx.x;
  int lp = gidx/96, col = gidx - lp*96;
  int pair = pair0 + lp;
  int qi = pair/24;
  int cc = col; bool isq = false;
  if (cc >= 48){ cc -= 48; isq = true; }
  int ci = cc>>4, e = cc&15;
  int f = e&7; bool is_sin = (e>=8);
  float coord;
  if (isq){
    coord = x_in[qi*3 + ci];
  } else {
    int pt = nb_idx[pair];
    int gcoord;
    if (ci==0) gcoord = pt/2304;
    else if (ci==1) gcoord = (pt/48)%48;
    else gcoord = pt%48;
    coord = gcoord*(1.0f/47.0f);
  }
  float freq = exp2f(-(float)f * 1.66096404744368117f);  // 10000^{-f/8}
  float ang = coord*freq;
  kin[gidx] = f2bf(is_sin ? sinf(ang) : cosf(ang));
}

// ---------------- MFMA GEMM: C[m][n] = act(sum_k A[m][k]*B[n][k] + bias[n]) ----------------
// A direct global->register; B staged in LDS via global_load_lds.
template<int ACT, int OUT_BF16>
__global__ __launch_bounds__(256) void k_gemm_mfma(
    const unsigned short* __restrict__ A, const unsigned short* __restrict__ B,
    const float* __restrict__ bias, void* __restrict__ Cout,
    int M, int N, int K)
{
  __shared__ unsigned short Bs[128*32];
  const int t = threadIdx.x;
  const int lane = t & 63, w = t >> 6;
  const int wm = w >> 1, wn = w & 1;
  const int m0 = blockIdx.x*128, n0 = blockIdx.y*128;
  const int lr = lane >> 2, lq = lane & 3;
  f32x4 acc[4][4];
  #pragma unroll
  for(int s=0;s<4;s++)
    #pragma unroll
    for(int n=0;n<4;n++) acc[s][n] = (f32x4){0.f,0.f,0.f,0.f};
  const unsigned short* Abase = A + (size_t)(m0 + wm*64 + (lane&15))*K + (lane>>4)*8;

  for(int k0=0;k0<K;k0+=32){
    __syncthreads();
    #pragma unroll
    for(int j=0;j<2;j++){
      int slot = w*2 + j;
      int row = slot*16 + lr;
      int brow = n0 + row; if (brow > N-1) brow = N-1;
      const unsigned short* gb = B + (size_t)brow*K + k0 + lq*8;
      __builtin_amdgcn_global_load_lds((const __attribute__((address_space(1))) void*)gb,
          (__attribute__((address_space(3))) void*)&Bs[slot*512], 16, 0, 0);
    }
    bf16x8 af[4];
    #pragma unroll
    for(int s=0;s<4;s++)
      af[s] = *(const bf16x8*)(Abase + (size_t)s*16*K + k0);
    __syncthreads();
    bf16x8 bg[4];
    #pragma unroll
    for(int n=0;n<4;n++)
      bg[n] = *(const bf16x8*)&Bs[(wn*64 + n*16 + (lane&15))*32 + (lane>>4)*8];
    #pragma unroll
    for(int s=0;s<4;s++)
      #pragma unroll
      for(int n=0;n<4;n++)
        acc[s][n] = __builtin_amdgcn_mfma_f32_16x16x32_bf16(af[s], bg[n], acc[s][n], 0, 0, 0);
  }

  unsigned short* Cb = (unsigned short*)Cout;
  float* Cf = (float*)Cout;
  const int colb = n0 + wn*64 + (lane&15);
  const int rowb = m0 + wm*64 + (lane>>4)*4;
  #pragma unroll
  for(int n=0;n<4;n++){
    int col = colb + n*16;
    if (col < N){
      float bn = bias[col];
      #pragma unroll
      for(int s=0;s<4;s++){
        int row = rowb + s*16;
        #pragma unroll
        for(int r=0;r<4;r++){
          float v = acc[s][n][r] + bn;
          if (ACT) v = gelu_f(v);
          if (OUT_BF16) Cb[(size_t)(row+r)*N + col] = f2bf(v);
          else          Cf[(size_t)(row+r)*N + col] = v;
        }
      }
    }
  }
}

// ---------------- GNO masked reduce -> U[8192][96] bf16 (one wave per query) ------------
__global__ __launch_bounds__(256) void k_gno_u(
    const float* __restrict__ K3, const float* __restrict__ FY,
    const int* __restrict__ nb_idx, const int* __restrict__ nb_mask,
    unsigned short* __restrict__ U)
{
  __shared__ int sidx[4][24];
  __shared__ float smk[4][24];
  const int t = threadIdx.x, w = t>>6, lane = t&63;
  const int i0 = blockIdx.x*4;
  if (t < 96){
    int q = t/24, k = t-24*q;
    int pt = nb_idx[(i0+q)*24+k];
    int x = pt/2304, rem = pt-2304*x, y = rem/48, z = rem-48*y;
    sidx[q][k] = x*2916 + y*54 + z;
    smk[q][k] = (nb_mask[(i0+q)*24+k] != 0)? 1.f : 0.f;
  }
  __syncthreads();
  const int i = i0 + w;
  const int c1 = lane, c2 = 64+lane;
  float a1=0.f, a2=0.f, den=0.f;
  for(int k=0;k<24;k++){
    float mk = smk[w][k];
    den += mk;
    if (mk > 0.f){
      const float* k3p = K3 + (size_t)(i*24+k)*CH;
      const float* fyp = FY + (size_t)sidx[w][k]*96;
      a1 += k3p[c1]*fyp[c1];
      if (c2 < CH) a2 += k3p[c2]*fyp[c2];
    }
  }
  if (den < 1.f) den = 1.f;
  U[(size_t)i*96 + c1] = f2bf(a1/den);
  if (c2 < 96) U[(size_t)i*96 + c2] = f2bf((c2 < CH)? a2/den : 0.f);
}

// ---------------- final dot: out[i] = H1[i]·p2w + p2b ----------------
__global__ __launch_bounds__(256) void k_out(const unsigned short* __restrict__ H1,
    const float* __restrict__ p2w, const float* __restrict__ p2b,
    float* __restrict__ out)
{
  const int t = threadIdx.x, w = t>>6, lane = t&63;
  const int i = blockIdx.x*4 + w;
  const unsigned short* hp = H1 + (size_t)i*256 + lane*4;
  float s = 0.f;
  #pragma unroll
  for(int j=0;j<4;j++) s += bf2f(hp[j]) * p2w[lane*4+j];
  #pragma unroll
  for(int off=32; off; off>>=1) s += __shfl_down(s, off, 64);
  if (lane==0) out[i] = s + p2b[0];
}

// ---------------- launch ----------------
extern "C" void kernel_launch(void* const* d_in, const int* in_sizes, int n_in,
                              void* d_out, int out_size, void* d_ws, size_t ws_size,
                              hipStream_t stream)
{
  (void)in_sizes; (void)n_in; (void)out_size; (void)ws_size;
  const float* x_in  = (const float*)d_in[0];
  const float* df    = (const float*)d_in[2];
  const int*   nbidx = (const int*)d_in[3];
  const int*   nbmsk = (const int*)d_in[4];
  const float* wlift = (const float*)d_in[5];
  const float* blift = (const float*)d_in[6];
  const float* spwr  = (const float*)d_in[7];
  const float* spwi  = (const float*)d_in[8];
  const float* wskip = (const float*)d_in[9];
  const float* bskip = (const float*)d_in[10];
  const float* m1w   = (const float*)d_in[11];
  const float* m1b   = (const float*)d_in[12];
  const float* m2w   = (const float*)d_in[13];
  const float* m2b   = (const float*)d_in[14];
  const float* wms   = (const float*)d_in[15];
  const float* bms   = (const float*)d_in[16];
  const float* g1w   = (const float*)d_in[17];
  const float* g1b   = (const float*)d_in[18];
  const float* g2w   = (const float*)d_in[19];
  const float* g2b   = (const float*)d_in[20];
  const float* k1w   = (const float*)d_in[21];
  const float* k1b   = (const float*)d_in[22];
  const float* k2w   = (const float*)d_in[23];
  const float* k2b   = (const float*)d_in[24];
  const float* k3w   = (const float*)d_in[25];
  const float* k3b   = (const float*)d_in[26];
  const float* p1w   = (const float*)d_in[27];
  const float* p1b   = (const float*)d_in[28];
  const float* p2w   = (const float*)d_in[29];
  const float* p2b   = (const float*)d_in[30];
  float* out = (float*)d_out;
  char* ws = (char*)d_ws;

  unsigned short* hAb = (unsigned short*)(ws + OFF_HA);
  float* hS = (float*)(ws + OFF_HS);
  unsigned short* Ab = (unsigned short*)(ws + OFF_AB);
  unsigned short* Bb = (unsigned short*)(ws + OFF_BB);
  float* Xsc = (float*)(ws + OFF_XSC);
  float* fA = (float*)(ws + OFF_FA);
  float* fB = (float*)(ws + OFF_FB);
  float* fC = (float*)(ws + OFF_FC);
  float* fD = (float*)(ws + OFF_FD);
  float* fE = (float*)(ws + OFF_FE);
  double* st= (double*)(ws + OFF_ST);
  unsigned short* Wb = (unsigned short*)(ws + OFF_WB);
  unsigned short* p1wb = (unsigned short*)(ws + OFF_P1W);
  unsigned short* w1b  = (unsigned short*)(ws + OFF_W1);
  unsigned short* w2b  = (unsigned short*)(ws + OFF_W2);
  unsigned short* w3b  = (unsigned short*)(ws + OFF_W3);
  float* K3 = (float*)(ws + OFF_K3);
  unsigned short* hT = (unsigned short*)(ws + OFF_HT);   // aliases K3 (FNO phase only)
  unsigned short* Z2b  = (unsigned short*)(ws + OFF_Z2);
  unsigned short* Ub   = (unsigned short*)(ws + OFF_U);
  unsigned short* H1b  = (unsigned short*)(ws + OFF_H1);
  unsigned short* kinb = (unsigned short*)(ws + OFF_KIN);
  unsigned short* Z1b  = (unsigned short*)(ws + OFF_Z1);

  k_zero_stats<<<1,64,0,stream>>>(st);
  k_wprep<<<dim3(36,4),256,0,stream>>>(wskip, Wb, 0);
  k_wprep<<<dim3(36,4),256,0,stream>>>(m1w,   Wb, 1);
  k_wprep<<<dim3(36,4),256,0,stream>>>(m2w,   Wb, 2);
  k_wprep<<<dim3(36,4),256,0,stream>>>(wms,   Wb, 3);
  k_pad_w<<<96,256,0,stream>>>(p1w, p1wb, 256);
  k_f2bf<<<(512*96+255)/256,256,0,stream>>>(k1w, w1b, 512*96);
  k_f2bf<<<(256*512+255)/256,256,0,stream>>>(k2w, w2b, 256*512);
  k_f2bf<<<(86*256+255)/256,256,0,stream>>>(k3w, w3b, 86*256);
  k_lift<<<1231,256,0,stream>>>(df, wlift, blift, hAb, Ab);

  for(int l=0;l<4;l++){
    const float* wr_l = spwr + (size_t)l*4*CH*CH*216;
    const float* wi_l = spwi + (size_t)l*4*CH*CH*216;
    double* st1 = st + l*4;
    double* st2 = st + l*4 + 2;
    k_dft_z<<<3919,256,0,stream>>>(hAb, fA);
    k_dft_y<<<1161,256,0,stream>>>(fA, fB);
    k_dft_x<<<86,256,0,stream>>>(fB, fC);
    k_mix<<<dim3(86,4),256,0,stream>>>(fC, wr_l, wi_l, fD);
    k_idft_x<<<86,256,0,stream>>>(fD, fE);
    k_idft_y<<<1161,256,0,stream>>>(fE, fA);
    k_idft_z<<<3919,256,0,stream>>>(fA, hS, st1);
    k_tr<<<1231,256,0,stream>>>(hS, hT);
    const unsigned short* Wl3 = Wb + (size_t)l*4*9216;
    const unsigned short* Wms = Wb + (size_t)(l*4+3)*9216;
    if (l<3){
      k_fuse3<1><<<1231,256,0,stream>>>(Ab, Wl3, bskip+l*86, m1b+l*86, m2b+l*86,
          hT, g1w+l*86, g1b+l*86, st1, st2, Bb, Xsc);
      k_convms<0><<<1231,256,0,stream>>>(Bb, Wms, bms+l*86, Xsc, g2w+l*86, g2b+l*86,
          st2, Ab, hAb, nullptr);
    } else {
      k_fuse3<0><<<1231,256,0,stream>>>(Ab, Wl3, bskip+l*86, m1b+l*86, m2b+l*86,
          hT, g1w+l*86, g1b+l*86, st1, st2, Bb, Xsc);
      k_convms<1><<<1231,256,0,stream>>>(Bb, Wms, bms+l*86, Xsc, g2w+l*86, g2b+l*86,
          st2, nullptr, nullptr, Xsc);
    }
  }

  for(int ch=0; ch<2; ch++){
    int pair0 = ch*CHUNK_M;
    k_build_kin<<<(CHUNK_M*96)/256,256,0,stream>>>(x_in, nbidx, kinb, pair0);
    k_gemm_mfma<1,1><<<dim3(CHUNK_M/128,4),256,0,stream>>>(kinb, w1b, k1b, (void*)Z1b, CHUNK_M, 512, 96);
    k_gemm_mfma<1,1><<<dim3(CHUNK_M/128,2),256,0,stream>>>(Z1b, w2b, k2b, (void*)Z2b, CHUNK_M, 256, 512);
    k_gemm_mfma<0,0><<<dim3(CHUNK_M/128,1),256,0,stream>>>(Z2b, w3b, k3b, (void*)(K3 + (size_t)pair0*CH), CHUNK_M, 86, 256);
  }

  k_gno_u<<<2048,256,0,stream>>>(K3, Xsc, nbidx, nbmsk, Ub);
  k_gemm_mfma<1,1><<<dim3(64,2),256,0,stream>>>(Ub, p1wb, p1b, (void*)H1b, 8192, 256, 96);
  k_out<<<2048,256,0,stream>>>(H1b, p2w, p2b, out);
}